// Round 7
// baseline (22184.483 us; speedup 1.0000x reference)
//
#include <hip/hip_runtime.h>

#define BB 8
#define TT 2000
#define DD 64
#define NN 2000
#define NWG 125
#define COLS 16
#define THREADS 512
#define SROW 2048          // bf16 elements per LDS row (4096 B, swizzled)
#define XST 68

// LDS: wS 16*2048*2=65536, sS 8*2048*2=32768, winS 16*68*4=4352, red 8*8*16*4=4096
#define LDS_BYTES (65536 + 32768 + 4352 + 4096)

typedef __bf16 bf16x8 __attribute__((ext_vector_type(8)));
typedef float f32x4 __attribute__((ext_vector_type(4)));

__device__ __forceinline__ float fast_tanh(float v) {
    float e = __expf(2.0f * v);
    return 1.0f - 2.0f / (e + 1.0f);
}

// ---- uncached (coherence-point) accessors: sc0 sc1 = bypass L1/L2, served by IC ----
__device__ __forceinline__ uint4 ld_uc4(const uint4* p) {
    uint4 v;
    asm volatile("global_load_dwordx4 %0, %1, off sc0 sc1" : "=v"(v) : "v"(p) : "memory");
    return v;
}
__device__ __forceinline__ void st_uc_u16(void* p, unsigned v) {
    asm volatile("global_store_short %0, %1, off sc0 sc1" :: "v"(p), "v"(v) : "memory");
}
__device__ __forceinline__ unsigned ld_uc_u32(const void* p) {
    unsigned v;
    asm volatile("global_load_dword %0, %1, off sc0 sc1\n\ts_waitcnt vmcnt(0)"
                 : "=v"(v) : "v"(p) : "memory");
    return v;
}

__global__ void __launch_bounds__(THREADS, 1)
esn_recur(const float* __restrict__ x, const float* __restrict__ Win,
          const float* __restrict__ Wres, __bf16* __restrict__ sG,
          float* __restrict__ H, unsigned* __restrict__ arr)
{
    extern __shared__ char smraw[];
    __bf16* wS   = (__bf16*)smraw;                 // [16][2048] swizzled: blk^(c&7)
    __bf16* sS   = wS + 16 * SROW;                 // [8][2048]  swizzled: blk^row
    float*  winS = (float*)(sS + 8 * SROW);        // [16][68]
    float*  red  = winS + 16 * XST;                // [8 waves][8 rows][16 cols]

    const int tid  = threadIdx.x;
    const int wg   = blockIdx.x;
    const int col0 = wg * COLS;
    const int wave = tid >> 6;
    const int lane = tid & 63;

    // zero all LDS (also zeroes K-pad 2000..2047 for the MFMA)
    for (int i = tid; i < LDS_BYTES / 4; i += THREADS) ((unsigned*)smraw)[i] = 0u;
    __syncthreads();

    // one-time: Wres slice transposed, bf16, XOR-swizzled 16B blocks
    {
        const int c = tid & 15, h = c & 7;
        for (int k = tid >> 4; k < NN; k += 32)
            wS[c * SROW + ((((k >> 3) ^ h) << 3) | (k & 7))] =
                (__bf16)Wres[(size_t)k * NN + col0 + c];
    }
    // one-time: Win slice (f32)
    for (int i = tid; i < COLS * DD; i += THREADS) {
        int c = i >> 6, d = i & 63;
        winS[c * XST + d] = Win[(size_t)d * NN + col0 + c];
    }
    __syncthreads();

    const int arow = lane & 7;        // A-fragment row (rows 8..15 dup 0..7)
    const int quad = lane >> 4;
    const int bcol = lane & 15;
    const int hb   = bcol & 7;
    const bool isfin = (tid < BB * COLS);   // 128 threads = waves 0,1 (wave-uniform)
    const int fb = tid >> 4, fc = tid & 15;

    for (int t = 0; t < TT; ++t) {
        // x@Win partial for THIS step — from L2-cached x, overlaps the poll wait
        float xacc = 0.f;
        if (isfin) {
            const float4* xr = (const float4*)(x + ((size_t)fb * TT + t) * DD);
            const float4* wv = (const float4*)(winS + fc * XST);
            float p0 = 0.f, p1 = 0.f, p2 = 0.f, p3 = 0.f;
            #pragma unroll
            for (int d4 = 0; d4 < 16; d4 += 4) {
                float4 x0 = xr[d4+0], x1 = xr[d4+1], x2 = xr[d4+2], x3 = xr[d4+3];
                float4 w0 = wv[d4+0], w1 = wv[d4+1], w2 = wv[d4+2], w3 = wv[d4+3];
                p0 = fmaf(x0.x,w0.x,p0); p0 = fmaf(x0.y,w0.y,p0);
                p0 = fmaf(x0.z,w0.z,p0); p0 = fmaf(x0.w,w0.w,p0);
                p1 = fmaf(x1.x,w1.x,p1); p1 = fmaf(x1.y,w1.y,p1);
                p1 = fmaf(x1.z,w1.z,p1); p1 = fmaf(x1.w,w1.w,p1);
                p2 = fmaf(x2.x,w2.x,p2); p2 = fmaf(x2.y,w2.y,p2);
                p2 = fmaf(x2.z,w2.z,p2); p2 = fmaf(x2.w,w2.w,p2);
                p3 = fmaf(x3.x,w3.x,p3); p3 = fmaf(x3.y,w3.y,p3);
                p3 = fmaf(x3.z,w3.z,p3); p3 = fmaf(x3.w,w3.w,p3);
            }
            xacc = (p0 + p1) + (p2 + p3);
        }

        if (t > 0) {
            // per-wave poll: lane 0 of EVERY wave polls the arrival counter
            // (4 B/iter/wave — byte-bounded spin), then the wave proceeds
            // straight to its row load. No intra-block release barrier.
            {
                unsigned v = 0;
                do {
                    if (lane == 0) v = ld_uc_u32(arr + t);
                    v = __builtin_amdgcn_readfirstlane(v);
                } while (v < 2 * NWG);
            }
            // load state row `wave` from IC (uncached), swizzled into LDS
            const uint4* srcRow =
                (const uint4*)(sG + (size_t)(t & 1) * (BB * NN) + wave * NN);
            uint4 v0 = ld_uc4(srcRow + lane);
            uint4 v1 = ld_uc4(srcRow + lane + 64);
            uint4 v2 = ld_uc4(srcRow + lane + 128);
            uint4 v3 = make_uint4(0u, 0u, 0u, 0u);
            const bool has4 = (lane < 58);         // 192+lane < 250
            if (has4) v3 = ld_uc4(srcRow + lane + 192);
            asm volatile("s_waitcnt vmcnt(0)" ::: "memory");
            __bf16* dst = sS + wave * SROW;
            *(uint4*)(dst + (size_t)((lane      ) ^ wave) * 8) = v0;
            *(uint4*)(dst + (size_t)((lane +  64) ^ wave) * 8) = v1;
            *(uint4*)(dst + (size_t)((lane + 128) ^ wave) * 8) = v2;
            if (has4) *(uint4*)(dst + (size_t)((lane + 192) ^ wave) * 8) = v3;
        }
        __syncthreads();   // staging (all rows) visible to all waves before MFMA

        // state @ Wres slice via MFMA: wave w owns K slice [w*256, (w+1)*256)
        f32x4 acc = {0.f, 0.f, 0.f, 0.f};
        if (t > 0) {
            const __bf16* aBase = sS + arow * SROW;
            const __bf16* bBase = wS + bcol * SROW;
            const int blk0 = wave * 32 + quad;
            #pragma unroll
            for (int m = 0; m < 8; ++m) {
                const int blk = blk0 + m * 4;
                bf16x8 a = *(const bf16x8*)(aBase + ((blk ^ arow) << 3));
                bf16x8 b = *(const bf16x8*)(bBase + ((blk ^ hb) << 3));
                acc = __builtin_amdgcn_mfma_f32_16x16x32_bf16(a, b, acc, 0, 0, 0);
            }
        }
        if (lane < 32) {
            const int r0 = (lane >> 4) * 4;
            #pragma unroll
            for (int i = 0; i < 4; ++i)
                red[(wave * 8 + r0 + i) * 16 + bcol] = acc[i];
        }
        __syncthreads();

        // finish (waves 0,1): sum K-partials + x@Win, tanh, publish, signal.
        // Each producer wave drains its OWN stores then fires its atomic —
        // no end-of-step barrier. Gate = 2 waves * 125 wgs = 250.
        if (isfin) {
            float a2 = xacc;
            #pragma unroll
            for (int w = 0; w < 8; ++w) a2 += red[(w * 8 + fb) * 16 + fc];
            float s = fast_tanh(a2);
            if (t < TT - 1) {
                __bf16 sb = (__bf16)s;
                unsigned short us;
                __builtin_memcpy(&us, &sb, 2);
                st_uc_u16(sG + (size_t)((t + 1) & 1) * (BB * NN) + fb * NN + col0 + fc,
                          (unsigned)us);
                asm volatile("s_waitcnt vmcnt(0)" ::: "memory");  // this wave's state at IC
                if ((tid & 63) == 0) atomicAdd(arr + t + 1, 1u);  // tid 0 and tid 64
            }
            float hval = (fc & 1) ? s : s * s;   // even global col -> square
            H[((size_t)t * BB + fb) * NN + col0 + fc] = hval;     // off the signal path
        }
        // waves 2..7 fall through to the next step's poll (self-gating)
    }
}

// out[b,t,:] = H[t,b,:] @ Wout  (augmentation already applied in H)
__global__ void __launch_bounds__(256, 1)
esn_out(const float* __restrict__ H, const float* __restrict__ Wout,
        float* __restrict__ out)
{
    __shared__ float Hs[64 * 84];
    __shared__ float Ws[80 * 64];
    const int tid = threadIdx.x;
    const int r0  = blockIdx.x * 64;      // global row = t*8 + b
    const int tr  = tid >> 4;             // 0..15
    const int tc  = tid & 15;             // 0..15
    float acc[4][4] = {{0.f}};

    for (int k0 = 0; k0 < NN; k0 += 80) {
        __syncthreads();
        #pragma unroll
        for (int j = 0; j < 5; ++j) {
            int idx = j * 256 + tid;               // 0..1279
            int r = idx / 20, q = idx % 20;
            *(float4*)&Hs[r * 84 + q * 4] =
                *(const float4*)&H[(size_t)(r0 + r) * NN + k0 + q * 4];
        }
        #pragma unroll
        for (int j = 0; j < 5; ++j) {
            int idx = j * 256 + tid;
            int kk = idx >> 4, c4 = idx & 15;
            *(float4*)&Ws[kk * 64 + c4 * 4] =
                *(const float4*)&Wout[(size_t)(k0 + kk) * DD + c4 * 4];
        }
        __syncthreads();
        for (int kk = 0; kk < 80; ++kk) {
            float4 wv = *(const float4*)&Ws[kk * 64 + tc * 4];
            #pragma unroll
            for (int i = 0; i < 4; ++i) {
                float hv = Hs[(tr + 16 * i) * 84 + kk];
                acc[i][0] = fmaf(hv, wv.x, acc[i][0]);
                acc[i][1] = fmaf(hv, wv.y, acc[i][1]);
                acc[i][2] = fmaf(hv, wv.z, acc[i][2]);
                acc[i][3] = fmaf(hv, wv.w, acc[i][3]);
            }
        }
    }
    #pragma unroll
    for (int i = 0; i < 4; ++i) {
        int rg = r0 + tr + 16 * i;
        int t = rg >> 3, b = rg & 7;
        *(float4*)&out[((size_t)b * TT + t) * DD + tc * 4] =
            make_float4(acc[i][0], acc[i][1], acc[i][2], acc[i][3]);
    }
}

extern "C" void kernel_launch(void* const* d_in, const int* in_sizes, int n_in,
                              void* d_out, int out_size, void* d_ws, size_t ws_size,
                              hipStream_t stream)
{
    const float* x    = (const float*)d_in[0];
    const float* Win  = (const float*)d_in[1];
    const float* Wres = (const float*)d_in[2];
    const float* Wout = (const float*)d_in[3];
    float* out = (float*)d_out;

    char* ws = (char*)d_ws;
    unsigned* arr = (unsigned*)ws;                   // 2000 dwords (8 KB reserved)
    __bf16* sG = (__bf16*)(ws + 8192);               // 2 * 8 * 2000 bf16 = 64 KB
    float* H   = (float*)(ws + 8192 + 65536);        // 2000*8*2000 f32 = 128 MB

    (void)hipMemsetAsync(d_ws, 0, 8192, stream);     // fresh arrival counters per call

    (void)hipFuncSetAttribute((const void*)esn_recur,
                              hipFuncAttributeMaxDynamicSharedMemorySize, LDS_BYTES);
    esn_recur<<<NWG, THREADS, LDS_BYTES, stream>>>(x, Win, Wres, sG, H, arr);
    esn_out<<<250, 256, 0, stream>>>(H, Wout, out);
}

// Round 8
// 10879.040 us; speedup vs baseline: 2.0392x; 2.0392x over previous
//
#include <hip/hip_runtime.h>

#define BB 8
#define TT 2000
#define DD 64
#define NN 2000
#define NWG 125
#define COLS 16
#define THREADS 512
#define SROW 2048          // bf16 elements per LDS row (4096 B, swizzled)
#define XST 68

// LDS: wS 16*2048*2=65536, sS 8*2048*2=32768, winS 16*68*4=4352, red 8*8*16*4=4096
#define LDS_BYTES (65536 + 32768 + 4352 + 4096)

typedef __bf16 bf16x8 __attribute__((ext_vector_type(8)));
typedef float f32x4 __attribute__((ext_vector_type(4)));

__device__ __forceinline__ float fast_tanh(float v) {
    float e = __expf(2.0f * v);
    return 1.0f - 2.0f / (e + 1.0f);
}

// ---- uncached (coherence-point) accessors: sc0 sc1 = bypass L1/L2, served by IC ----
__device__ __forceinline__ uint4 ld_uc4(const uint4* p) {
    uint4 v;
    asm volatile("global_load_dwordx4 %0, %1, off sc0 sc1" : "=v"(v) : "v"(p) : "memory");
    return v;
}
__device__ __forceinline__ void st_uc_u16(void* p, unsigned v) {
    asm volatile("global_store_short %0, %1, off sc0 sc1" :: "v"(p), "v"(v) : "memory");
}
__device__ __forceinline__ void st_uc_u32(void* p, unsigned v) {
    asm volatile("global_store_dword %0, %1, off sc0 sc1" :: "v"(p), "v"(v) : "memory");
}
// paired uncached load: both in flight, single wait -> one IC round-trip
__device__ __forceinline__ void ld2_uc_u32(const unsigned* p0, const unsigned* p1,
                                           unsigned& a, unsigned& b) {
    asm volatile("global_load_dword %0, %2, off sc0 sc1\n\t"
                 "global_load_dword %1, %3, off sc0 sc1\n\t"
                 "s_waitcnt vmcnt(0)"
                 : "=&v"(a), "=&v"(b) : "v"(p0), "v"(p1) : "memory");
}

__global__ void __launch_bounds__(THREADS, 1)
esn_recur(const float* __restrict__ x, const float* __restrict__ Win,
          const float* __restrict__ Wres, __bf16* __restrict__ sG,
          float* __restrict__ H, unsigned* __restrict__ flags)
{
    extern __shared__ char smraw[];
    __bf16* wS   = (__bf16*)smraw;                 // [16][2048] swizzled: blk^(c&7)
    __bf16* sS   = wS + 16 * SROW;                 // [8][2048]  swizzled: blk^row
    float*  winS = (float*)(sS + 8 * SROW);        // [16][68]
    float*  red  = winS + 16 * XST;                // [8 waves][8 rows][16 cols]

    const int tid  = threadIdx.x;
    const int wg   = blockIdx.x;
    const int col0 = wg * COLS;
    const int wave = tid >> 6;
    const int lane = tid & 63;

    // zero all LDS (also zeroes K-pad 2000..2047 for the MFMA)
    for (int i = tid; i < LDS_BYTES / 4; i += THREADS) ((unsigned*)smraw)[i] = 0u;
    __syncthreads();

    // one-time: Wres slice transposed, bf16, XOR-swizzled 16B blocks
    {
        const int c = tid & 15, h = c & 7;
        for (int k = tid >> 4; k < NN; k += 32)
            wS[c * SROW + ((((k >> 3) ^ h) << 3) | (k & 7))] =
                (__bf16)Wres[(size_t)k * NN + col0 + c];
    }
    // one-time: Win slice (f32)
    for (int i = tid; i < COLS * DD; i += THREADS) {
        int c = i >> 6, d = i & 63;
        winS[c * XST + d] = Win[(size_t)d * NN + col0 + c];
    }
    __syncthreads();

    const int arow = lane & 7;        // A-fragment row (rows 8..15 dup 0..7)
    const int quad = lane >> 4;
    const int bcol = lane & 15;
    const int hb   = bcol & 7;
    // producer wave 1: 2 outputs/thread -> rows fb and fb+4, col fc
    const int fb = lane >> 4, fc = lane & 15;
    // poller wave 0: 2 flag slots/lane covering 0..124
    const unsigned* f1 = flags + lane;
    const unsigned* f2 = flags + ((lane < 61) ? (64 + lane) : 0);

    for (int t = 0; t < TT; ++t) {
        // x@Win partials (producer wave only) — L2-cached x, off wave 0's path
        float xa0 = 0.f, xa1 = 0.f;
        if (wave == 1) {
            const float4* xr0 = (const float4*)(x + ((size_t)fb * TT + t) * DD);
            const float4* xr1 = (const float4*)(x + ((size_t)(fb + 4) * TT + t) * DD);
            const float4* wv  = (const float4*)(winS + fc * XST);
            #pragma unroll
            for (int d4 = 0; d4 < 16; ++d4) {
                float4 w = wv[d4];
                float4 u0 = xr0[d4], u1 = xr1[d4];
                xa0 = fmaf(u0.x, w.x, xa0); xa0 = fmaf(u0.y, w.y, xa0);
                xa0 = fmaf(u0.z, w.z, xa0); xa0 = fmaf(u0.w, w.w, xa0);
                xa1 = fmaf(u1.x, w.x, xa1); xa1 = fmaf(u1.y, w.y, xa1);
                xa1 = fmaf(u1.z, w.z, xa1); xa1 = fmaf(u1.w, w.w, xa1);
            }
        }

        if (t > 0) {
            // wave 0: read all 125 per-wg flags in one paired round-trip
            if (wave == 0) {
                const unsigned tgt = (unsigned)t;
                unsigned a, b;
                do {
                    ld2_uc_u32(f1, f2, a, b);
                } while (!__all((a >= tgt) && (b >= tgt)));
            }
            __builtin_amdgcn_s_barrier();          // release: state_t certified at IC
            // load state row `wave` from IC (uncached), swizzled into LDS
            const uint4* srcRow =
                (const uint4*)(sG + (size_t)(t & 1) * (BB * NN) + wave * NN);
            uint4 v0 = ld_uc4(srcRow + lane);
            uint4 v1 = ld_uc4(srcRow + lane + 64);
            uint4 v2 = ld_uc4(srcRow + lane + 128);
            uint4 v3 = make_uint4(0u, 0u, 0u, 0u);
            const bool has4 = (lane < 58);         // 192+lane < 250
            if (has4) v3 = ld_uc4(srcRow + lane + 192);
            asm volatile("s_waitcnt vmcnt(0)" ::: "memory");
            __bf16* dst = sS + wave * SROW;
            *(uint4*)(dst + (size_t)((lane      ) ^ wave) * 8) = v0;
            *(uint4*)(dst + (size_t)((lane +  64) ^ wave) * 8) = v1;
            *(uint4*)(dst + (size_t)((lane + 128) ^ wave) * 8) = v2;
            if (has4) *(uint4*)(dst + (size_t)((lane + 192) ^ wave) * 8) = v3;
        }
        __syncthreads();   // staging (all rows) visible to all waves before MFMA

        // state @ Wres slice via MFMA: wave w owns K slice [w*256, (w+1)*256)
        f32x4 acc = {0.f, 0.f, 0.f, 0.f};
        if (t > 0) {
            const __bf16* aBase = sS + arow * SROW;
            const __bf16* bBase = wS + bcol * SROW;
            const int blk0 = wave * 32 + quad;
            #pragma unroll
            for (int m = 0; m < 8; ++m) {
                const int blk = blk0 + m * 4;
                bf16x8 a = *(const bf16x8*)(aBase + ((blk ^ arow) << 3));
                bf16x8 b = *(const bf16x8*)(bBase + ((blk ^ hb) << 3));
                acc = __builtin_amdgcn_mfma_f32_16x16x32_bf16(a, b, acc, 0, 0, 0);
            }
        }
        if (lane < 32) {
            const int r0 = (lane >> 4) * 4;
            #pragma unroll
            for (int i = 0; i < 4; ++i)
                red[(wave * 8 + r0 + i) * 16 + bcol] = acc[i];
        }
        __syncthreads();

        // finish (wave 1 only): 2 outputs/thread; drain own stores, then ONE
        // plain uncached flag store (no atomic, no end-of-step barrier).
        if (wave == 1) {
            float a0 = xa0, a1 = xa1;
            #pragma unroll
            for (int w = 0; w < 8; ++w) {
                a0 += red[(w * 8 + fb    ) * 16 + fc];
                a1 += red[(w * 8 + fb + 4) * 16 + fc];
            }
            float s0 = fast_tanh(a0);
            float s1 = fast_tanh(a1);
            if (t < TT - 1) {
                __bf16 b0 = (__bf16)s0, b1 = (__bf16)s1;
                unsigned short u0, u1;
                __builtin_memcpy(&u0, &b0, 2);
                __builtin_memcpy(&u1, &b1, 2);
                __bf16* dstG = sG + (size_t)((t + 1) & 1) * (BB * NN) + col0 + fc;
                st_uc_u16(dstG + (size_t)fb * NN,       (unsigned)u0);
                st_uc_u16(dstG + (size_t)(fb + 4) * NN, (unsigned)u1);
                asm volatile("s_waitcnt vmcnt(0)" ::: "memory");  // wave's state at IC
                if (lane == 0) st_uc_u32(flags + wg, (unsigned)(t + 1));
            }
            float h0 = (fc & 1) ? s0 : s0 * s0;   // even global col -> square
            float h1 = (fc & 1) ? s1 : s1 * s1;
            H[((size_t)t * BB + fb    ) * NN + col0 + fc] = h0;   // off signal path
            H[((size_t)t * BB + fb + 4) * NN + col0 + fc] = h1;
        }
        // waves 0,2..7 fall straight through to the next step's poll/barrier
    }
}

// out[b,t,:] = H[t,b,:] @ Wout  (augmentation already applied in H)
__global__ void __launch_bounds__(256, 1)
esn_out(const float* __restrict__ H, const float* __restrict__ Wout,
        float* __restrict__ out)
{
    __shared__ float Hs[64 * 84];
    __shared__ float Ws[80 * 64];
    const int tid = threadIdx.x;
    const int r0  = blockIdx.x * 64;      // global row = t*8 + b
    const int tr  = tid >> 4;             // 0..15
    const int tc  = tid & 15;             // 0..15
    float acc[4][4] = {{0.f}};

    for (int k0 = 0; k0 < NN; k0 += 80) {
        __syncthreads();
        #pragma unroll
        for (int j = 0; j < 5; ++j) {
            int idx = j * 256 + tid;               // 0..1279
            int r = idx / 20, q = idx % 20;
            *(float4*)&Hs[r * 84 + q * 4] =
                *(const float4*)&H[(size_t)(r0 + r) * NN + k0 + q * 4];
        }
        #pragma unroll
        for (int j = 0; j < 5; ++j) {
            int idx = j * 256 + tid;
            int kk = idx >> 4, c4 = idx & 15;
            *(float4*)&Ws[kk * 64 + c4 * 4] =
                *(const float4*)&Wout[(size_t)(k0 + kk) * DD + c4 * 4];
        }
        __syncthreads();
        for (int kk = 0; kk < 80; ++kk) {
            float4 wv = *(const float4*)&Ws[kk * 64 + tc * 4];
            #pragma unroll
            for (int i = 0; i < 4; ++i) {
                float hv = Hs[(tr + 16 * i) * 84 + kk];
                acc[i][0] = fmaf(hv, wv.x, acc[i][0]);
                acc[i][1] = fmaf(hv, wv.y, acc[i][1]);
                acc[i][2] = fmaf(hv, wv.z, acc[i][2]);
                acc[i][3] = fmaf(hv, wv.w, acc[i][3]);
            }
        }
    }
    #pragma unroll
    for (int i = 0; i < 4; ++i) {
        int rg = r0 + tr + 16 * i;
        int t = rg >> 3, b = rg & 7;
        *(float4*)&out[((size_t)b * TT + t) * DD + tc * 4] =
            make_float4(acc[i][0], acc[i][1], acc[i][2], acc[i][3]);
    }
}

extern "C" void kernel_launch(void* const* d_in, const int* in_sizes, int n_in,
                              void* d_out, int out_size, void* d_ws, size_t ws_size,
                              hipStream_t stream)
{
    const float* x    = (const float*)d_in[0];
    const float* Win  = (const float*)d_in[1];
    const float* Wres = (const float*)d_in[2];
    const float* Wout = (const float*)d_in[3];
    float* out = (float*)d_out;

    char* ws = (char*)d_ws;
    unsigned* flags = (unsigned*)ws;                 // 125 dwords (512 B, 4 lines)
    __bf16* sG = (__bf16*)(ws + 4096);               // 2 * 8 * 2000 bf16 = 64 KB
    float* H   = (float*)(ws + 4096 + 65536);        // 2000*8*2000 f32 = 128 MB

    (void)hipMemsetAsync(d_ws, 0, 4096, stream);     // fresh flags per call (replay-safe)

    (void)hipFuncSetAttribute((const void*)esn_recur,
                              hipFuncAttributeMaxDynamicSharedMemorySize, LDS_BYTES);
    esn_recur<<<NWG, THREADS, LDS_BYTES, stream>>>(x, Win, Wres, sG, H, flags);
    esn_out<<<250, 256, 0, stream>>>(H, Wout, out);
}

// Round 9
// 6618.835 us; speedup vs baseline: 3.3517x; 1.6436x over previous
//
#include <hip/hip_runtime.h>

#define BB 8
#define TT 2000
#define DD 64
#define NN 2000
#define NWG 125
#define COLS 16
#define THREADS 512
#define SROW 2048          // bf16 elements per LDS row (4096 B, swizzled)
#define XST 68

// LDS: wS 16*2048*2=65536, sS 8*2048*2=32768, winS 16*68*4=4352, red 8*8*16*4=4096
#define LDS_BYTES (65536 + 32768 + 4352 + 4096)

typedef __bf16 bf16x8 __attribute__((ext_vector_type(8)));
typedef float f32x4 __attribute__((ext_vector_type(4)));

__device__ __forceinline__ float fast_tanh(float v) {
    float e = __expf(2.0f * v);
    return 1.0f - 2.0f / (e + 1.0f);
}

// ---- uncached (coherence-point) accessors: sc0 sc1 = bypass L1/L2, served by IC ----
__device__ __forceinline__ uint4 ld_uc4(const uint4* p) {
    uint4 v;
    asm volatile("global_load_dwordx4 %0, %1, off sc0 sc1" : "=v"(v) : "v"(p) : "memory");
    return v;
}
__device__ __forceinline__ void st_uc_u16(void* p, unsigned v) {
    asm volatile("global_store_short %0, %1, off sc0 sc1" :: "v"(p), "v"(v) : "memory");
}
__device__ __forceinline__ void st_uc_u32(void* p, unsigned v) {
    asm volatile("global_store_dword %0, %1, off sc0 sc1" :: "v"(p), "v"(v) : "memory");
}
__device__ __forceinline__ unsigned ld_uc_u32(const void* p) {
    unsigned v;
    asm volatile("global_load_dword %0, %1, off sc0 sc1\n\ts_waitcnt vmcnt(0)"
                 : "=v"(v) : "v"(p) : "memory");
    return v;
}
// paired uncached load: both in flight, single wait -> one IC round-trip
__device__ __forceinline__ void ld2_uc_u32(const unsigned* p0, const unsigned* p1,
                                           unsigned& a, unsigned& b) {
    asm volatile("global_load_dword %0, %2, off sc0 sc1\n\t"
                 "global_load_dword %1, %3, off sc0 sc1\n\t"
                 "s_waitcnt vmcnt(0)"
                 : "=&v"(a), "=&v"(b) : "v"(p0), "v"(p1) : "memory");
}

__global__ void __launch_bounds__(THREADS, 1)
esn_recur(const float* __restrict__ x, const float* __restrict__ Win,
          const float* __restrict__ Wres, __bf16* __restrict__ sG,
          float* __restrict__ H, unsigned* __restrict__ flags,
          unsigned* __restrict__ gen)
{
    extern __shared__ char smraw[];
    __bf16* wS   = (__bf16*)smraw;                 // [16][2048] swizzled: blk^(c&7)
    __bf16* sS   = wS + 16 * SROW;                 // [8][2048]  swizzled: blk^row
    float*  winS = (float*)(sS + 8 * SROW);        // [16][68]
    float*  red  = winS + 16 * XST;                // [8 waves][8 rows][16 cols]

    const int tid  = threadIdx.x;
    const int wg   = blockIdx.x;
    const int col0 = wg * COLS;
    const int wave = tid >> 6;
    const int lane = tid & 63;

    // zero all LDS (also zeroes K-pad 2000..2047 for the MFMA)
    for (int i = tid; i < LDS_BYTES / 4; i += THREADS) ((unsigned*)smraw)[i] = 0u;
    __syncthreads();

    // one-time: Wres slice transposed, bf16, XOR-swizzled 16B blocks
    {
        const int c = tid & 15, h = c & 7;
        for (int k = tid >> 4; k < NN; k += 32)
            wS[c * SROW + ((((k >> 3) ^ h) << 3) | (k & 7))] =
                (__bf16)Wres[(size_t)k * NN + col0 + c];
    }
    // one-time: Win slice (f32)
    for (int i = tid; i < COLS * DD; i += THREADS) {
        int c = i >> 6, d = i & 63;
        winS[c * XST + d] = Win[(size_t)d * NN + col0 + c];
    }
    __syncthreads();

    const int arow = lane & 7;        // A-fragment row (rows 8..15 dup 0..7)
    const int quad = lane >> 4;
    const int bcol = lane & 15;
    const int hb   = bcol & 7;
    // producer wave 1: 2 outputs/thread -> rows fb and fb+4, col fc
    const int fb = lane >> 4, fc = lane & 15;
    // aggregator (wg 0, wave 0): 2 flag slots/lane covering 0..124
    const unsigned* f1 = flags + lane;
    const unsigned* f2 = flags + ((lane < 61) ? (64 + lane) : 0);

    for (int t = 0; t < TT; ++t) {
        // x@Win partials (producer wave only) — L2-cached x, off the signal path
        float xa0 = 0.f, xa1 = 0.f;
        if (wave == 1) {
            const float4* xr0 = (const float4*)(x + ((size_t)fb * TT + t) * DD);
            const float4* xr1 = (const float4*)(x + ((size_t)(fb + 4) * TT + t) * DD);
            const float4* wv  = (const float4*)(winS + fc * XST);
            #pragma unroll
            for (int d4 = 0; d4 < 16; ++d4) {
                float4 w = wv[d4];
                float4 u0 = xr0[d4], u1 = xr1[d4];
                xa0 = fmaf(u0.x, w.x, xa0); xa0 = fmaf(u0.y, w.y, xa0);
                xa0 = fmaf(u0.z, w.z, xa0); xa0 = fmaf(u0.w, w.w, xa0);
                xa1 = fmaf(u1.x, w.x, xa1); xa1 = fmaf(u1.y, w.y, xa1);
                xa1 = fmaf(u1.z, w.z, xa1); xa1 = fmaf(u1.w, w.w, xa1);
            }
        }

        if (t > 0) {
            // two-level signal: ONE sweeper (wg0/wave0) reads the 125 flags,
            // publishes gen; everyone else single-lane polls gen (1 line).
            if (wave == 0) {
                const unsigned tgt = (unsigned)t;
                if (wg == 0) {
                    unsigned a, b;
                    do {
                        ld2_uc_u32(f1, f2, a, b);
                    } while (!__all((a >= tgt) && (b >= tgt)));
                    if (lane == 0) st_uc_u32(gen, tgt);
                } else {
                    unsigned v = 0;
                    do {
                        if (lane == 0) v = ld_uc_u32(gen);
                        v = __builtin_amdgcn_readfirstlane(v);
                    } while (v < tgt);
                }
            }
            __builtin_amdgcn_s_barrier();          // release: state_t certified at IC
            // load state row `wave` from IC (uncached), swizzled into LDS
            const uint4* srcRow =
                (const uint4*)(sG + (size_t)(t & 1) * (BB * NN) + wave * NN);
            uint4 v0 = ld_uc4(srcRow + lane);
            uint4 v1 = ld_uc4(srcRow + lane + 64);
            uint4 v2 = ld_uc4(srcRow + lane + 128);
            uint4 v3 = make_uint4(0u, 0u, 0u, 0u);
            const bool has4 = (lane < 58);         // 192+lane < 250
            if (has4) v3 = ld_uc4(srcRow + lane + 192);
            asm volatile("s_waitcnt vmcnt(0)" ::: "memory");
            __bf16* dst = sS + wave * SROW;
            *(uint4*)(dst + (size_t)((lane      ) ^ wave) * 8) = v0;
            *(uint4*)(dst + (size_t)((lane +  64) ^ wave) * 8) = v1;
            *(uint4*)(dst + (size_t)((lane + 128) ^ wave) * 8) = v2;
            if (has4) *(uint4*)(dst + (size_t)((lane + 192) ^ wave) * 8) = v3;
        }
        __syncthreads();   // staging (all rows) visible to all waves before MFMA

        // state @ Wres slice via MFMA: wave w owns K slice [w*256, (w+1)*256)
        f32x4 acc = {0.f, 0.f, 0.f, 0.f};
        if (t > 0) {
            const __bf16* aBase = sS + arow * SROW;
            const __bf16* bBase = wS + bcol * SROW;
            const int blk0 = wave * 32 + quad;
            #pragma unroll
            for (int m = 0; m < 8; ++m) {
                const int blk = blk0 + m * 4;
                bf16x8 a = *(const bf16x8*)(aBase + ((blk ^ arow) << 3));
                bf16x8 b = *(const bf16x8*)(bBase + ((blk ^ hb) << 3));
                acc = __builtin_amdgcn_mfma_f32_16x16x32_bf16(a, b, acc, 0, 0, 0);
            }
        }
        if (lane < 32) {
            const int r0 = (lane >> 4) * 4;
            #pragma unroll
            for (int i = 0; i < 4; ++i)
                red[(wave * 8 + r0 + i) * 16 + bcol] = acc[i];
        }
        __syncthreads();

        // finish (wave 1 only): 2 outputs/thread; drain own stores, then ONE
        // plain uncached flag store (no atomic, no end-of-step barrier).
        if (wave == 1) {
            float a0 = xa0, a1 = xa1;
            #pragma unroll
            for (int w = 0; w < 8; ++w) {
                a0 += red[(w * 8 + fb    ) * 16 + fc];
                a1 += red[(w * 8 + fb + 4) * 16 + fc];
            }
            float s0 = fast_tanh(a0);
            float s1 = fast_tanh(a1);
            if (t < TT - 1) {
                __bf16 b0 = (__bf16)s0, b1 = (__bf16)s1;
                unsigned short u0, u1;
                __builtin_memcpy(&u0, &b0, 2);
                __builtin_memcpy(&u1, &b1, 2);
                __bf16* dstG = sG + (size_t)((t + 1) & 1) * (BB * NN) + col0 + fc;
                st_uc_u16(dstG + (size_t)fb * NN,       (unsigned)u0);
                st_uc_u16(dstG + (size_t)(fb + 4) * NN, (unsigned)u1);
                asm volatile("s_waitcnt vmcnt(0)" ::: "memory");  // wave's state at IC
                if (lane == 0) st_uc_u32(flags + wg, (unsigned)(t + 1));
            }
            float h0 = (fc & 1) ? s0 : s0 * s0;   // even global col -> square
            float h1 = (fc & 1) ? s1 : s1 * s1;
            H[((size_t)t * BB + fb    ) * NN + col0 + fc] = h0;   // off signal path
            H[((size_t)t * BB + fb + 4) * NN + col0 + fc] = h1;
        }
        // waves 0,2..7 fall straight through to the next step's poll/barrier
    }
}

// out[b,t,:] = H[t,b,:] @ Wout  (augmentation already applied in H)
__global__ void __launch_bounds__(256, 1)
esn_out(const float* __restrict__ H, const float* __restrict__ Wout,
        float* __restrict__ out)
{
    __shared__ float Hs[64 * 84];
    __shared__ float Ws[80 * 64];
    const int tid = threadIdx.x;
    const int r0  = blockIdx.x * 64;      // global row = t*8 + b
    const int tr  = tid >> 4;             // 0..15
    const int tc  = tid & 15;             // 0..15
    float acc[4][4] = {{0.f}};

    for (int k0 = 0; k0 < NN; k0 += 80) {
        __syncthreads();
        #pragma unroll
        for (int j = 0; j < 5; ++j) {
            int idx = j * 256 + tid;               // 0..1279
            int r = idx / 20, q = idx % 20;
            *(float4*)&Hs[r * 84 + q * 4] =
                *(const float4*)&H[(size_t)(r0 + r) * NN + k0 + q * 4];
        }
        #pragma unroll
        for (int j = 0; j < 5; ++j) {
            int idx = j * 256 + tid;
            int kk = idx >> 4, c4 = idx & 15;
            *(float4*)&Ws[kk * 64 + c4 * 4] =
                *(const float4*)&Wout[(size_t)(k0 + kk) * DD + c4 * 4];
        }
        __syncthreads();
        for (int kk = 0; kk < 80; ++kk) {
            float4 wv = *(const float4*)&Ws[kk * 64 + tc * 4];
            #pragma unroll
            for (int i = 0; i < 4; ++i) {
                float hv = Hs[(tr + 16 * i) * 84 + kk];
                acc[i][0] = fmaf(hv, wv.x, acc[i][0]);
                acc[i][1] = fmaf(hv, wv.y, acc[i][1]);
                acc[i][2] = fmaf(hv, wv.z, acc[i][2]);
                acc[i][3] = fmaf(hv, wv.w, acc[i][3]);
            }
        }
    }
    #pragma unroll
    for (int i = 0; i < 4; ++i) {
        int rg = r0 + tr + 16 * i;
        int t = rg >> 3, b = rg & 7;
        *(float4*)&out[((size_t)b * TT + t) * DD + tc * 4] =
            make_float4(acc[i][0], acc[i][1], acc[i][2], acc[i][3]);
    }
}

extern "C" void kernel_launch(void* const* d_in, const int* in_sizes, int n_in,
                              void* d_out, int out_size, void* d_ws, size_t ws_size,
                              hipStream_t stream)
{
    const float* x    = (const float*)d_in[0];
    const float* Win  = (const float*)d_in[1];
    const float* Wres = (const float*)d_in[2];
    const float* Wout = (const float*)d_in[3];
    float* out = (float*)d_out;

    char* ws = (char*)d_ws;
    unsigned* flags = (unsigned*)ws;                 // 125 dwords (512 B)
    unsigned* gen   = (unsigned*)(ws + 2048);        // own cache line
    __bf16* sG = (__bf16*)(ws + 4096);               // 2 * 8 * 2000 bf16 = 64 KB
    float* H   = (float*)(ws + 4096 + 65536);        // 2000*8*2000 f32 = 128 MB

    (void)hipMemsetAsync(d_ws, 0, 4096, stream);     // fresh flags+gen per call

    (void)hipFuncSetAttribute((const void*)esn_recur,
                              hipFuncAttributeMaxDynamicSharedMemorySize, LDS_BYTES);
    esn_recur<<<NWG, THREADS, LDS_BYTES, stream>>>(x, Win, Wres, sG, H, flags, gen);
    esn_out<<<250, 256, 0, stream>>>(H, Wout, out);
}